// Round 1
// baseline (206.934 us; speedup 1.0000x reference)
//
#include <hip/hip_runtime.h>
#include <hip/hip_bf16.h>
#include <math.h>

// VOCAB=50000, EMBED=256, MAXLEN=512, UNITS=32, F1=16, BATCH=512.
#define TT 512
#define BB 512
#define EE 256
#define UU 32
#define FF1 16
#define NWAVE 2048            // proj waves: 8/CU, 2/SIMD

// tanh(x) = 1 - 2/(e^{2x}+1), branch-free (exp2+rcp HW approx).
__device__ __forceinline__ float fast_tanh(float x) {
    float e = __builtin_amdgcn_exp2f(x * 2.8853900817779268f);  // e^{2x}
    float r = __builtin_amdgcn_rcpf(e + 1.0f);
    return fmaf(-2.0f, r, 1.0f);
}

__device__ __forceinline__ float rdlane(float v, int lane) {
    return __int_as_float(__builtin_amdgcn_readlane(__float_as_int(v), lane));
}

// v += value from lane (i - N) within the 16-lane DPP row (0 past row edge).
// VALU-pipe cross-lane: rocPRIM reduction pattern, ctrl = 0x110|N (row_shr:N).
#define DPP_ADD(v, ctrl)                                                    \
    (v) += __int_as_float(__builtin_amdgcn_update_dpp(                      \
        0, __float_as_int(v), (ctrl), 0xf, 0xf, true))

// ---------------------------------------------------------------------------
// Kernel A (unchanged, proven): P[r][u] = emb[r] @ Wx[:,u] + bias[u].
// DPP-reduce GEMV; ~memory-floor bound (~8 us).
// ---------------------------------------------------------------------------
__global__ __launch_bounds__(64) void proj_dpp(
    const float* __restrict__ emb, const float* __restrict__ Wx,
    const float* __restrict__ bias, float* __restrict__ P, int nrows)
{
    const int L = threadIdx.x;
    const int g = L >> 4;              // u-octet 0..3
    const int c = L & 15;              // k-lane 0..15
    const int wv = blockIdx.x;         // 0..NWAVE-1

    // ---- one-time coalesced w preload: w[kk][uu] = Wx[c+16*kk][g*8+uu]
    float w[16][8];
    #pragma unroll
    for (int kk = 0; kk < 16; ++kk) {
        const float4* src = (const float4*)(Wx + (size_t)(kk * 16 + c) * UU + g * 8);
        float4 a = src[0], b = src[1];
        w[kk][0] = a.x; w[kk][1] = a.y; w[kk][2] = a.z; w[kk][3] = a.w;
        w[kk][4] = b.x; w[kk][5] = b.y; w[kk][6] = b.z; w[kk][7] = b.w;
    }
    float bs[8];
    #pragma unroll
    for (int uu = 0; uu < 8; ++uu) bs[uu] = bias[g * 8 + uu];

    // rows handled by this wave: r = wv + NWAVE*i
    auto rowptr = [&](int i) {
        int r = wv + NWAVE * i;
        if (r >= nrows) r = nrows - 1;             // clamped dummy
        return emb + (size_t)r * EE;
    };

    float xA[16], xB[16];
    {
        const float* rp = rowptr(0);
        #pragma unroll
        for (int kk = 0; kk < 16; ++kk) xA[kk] = rp[kk * 16 + c];
    }

    const int NI = (nrows - 1 - wv) / NWAVE + 1;   // #valid rows (wv < nrows)

    for (int i = 0; i < NI; ++i) {
        // prefetch next row (clamped at tail)
        {
            const float* rp = rowptr(i + 1 < NI ? i + 1 : i);
            #pragma unroll
            for (int kk = 0; kk < 16; ++kk) xB[kk] = rp[kk * 16 + c];
        }

        // partials for this lane's 16 k's x 8 u's
        float p[8];
        #pragma unroll
        for (int uu = 0; uu < 8; ++uu) p[uu] = 0.f;
        #pragma unroll
        for (int kk = 0; kk < 16; ++kk) {
            const float xk = xA[kk];
            #pragma unroll
            for (int uu = 0; uu < 8; ++uu)
                p[uu] = fmaf(xk, w[kk][uu], p[uu]);
        }

        // reduce over the 16 c-lanes (DPP row-of-16); lane c==15 holds sums
        #pragma unroll
        for (int uu = 0; uu < 8; ++uu) {
            DPP_ADD(p[uu], 0x111);   // row_shr:1
            DPP_ADD(p[uu], 0x112);   // row_shr:2
            DPP_ADD(p[uu], 0x114);   // row_shr:4
            DPP_ADD(p[uu], 0x118);   // row_shr:8
        }

        if (c == 15) {
            const int r = wv + NWAVE * i;
            float4 o0, o1;
            o0.x = p[0] + bs[0]; o0.y = p[1] + bs[1];
            o0.z = p[2] + bs[2]; o0.w = p[3] + bs[3];
            o1.x = p[4] + bs[4]; o1.y = p[5] + bs[5];
            o1.z = p[6] + bs[6]; o1.w = p[7] + bs[7];
            float4* dst = (float4*)(P + (size_t)r * UU + g * 8);
            dst[0] = o0; dst[1] = o1;
        }

        #pragma unroll
        for (int kk = 0; kk < 16; ++kk) xA[kk] = xB[kk];
    }
}

// ---------------------------------------------------------------------------
// Kernel B v7: split-k scan.
// h_t = tanh(x_t + h_{t-1} @ Wh); fused heads + sigmoid.
// One batch row per 64-lane wave. NEW vs round-6:
//  * Lanes 0-31 accumulate k=0..15, lanes 32-63 accumulate k=16..31 for the
//    SAME output u=L&31 (round-6 had the upper half duplicating the lower).
//  * h broadcast via 16 ds_bpermute (per-lane addr (half*16+kk)*4) instead of
//    32 v_readlane: per-half-divergent sources, LDS pipe instead of VALU.
//  * Cross-half combine: v_permlane32_swap + add -> both halves hold the full
//    pre-activation; h stays replicated (lane i holds h_{i&31}) so bpermute
//    sources, LDS x-reads, and heads stay valid.
//  * x_t folded into lower-half acc0 only (masked at prefetch, off-chain).
// Per step: 16 bperm + 16 FMA (4-deep) + 3 add + swap + tanh  (~44 instrs,
// was ~75; chain ~160cy, was ~350).
// ---------------------------------------------------------------------------
__global__ __launch_bounds__(64) void scan_heads(
    const int* __restrict__ tokens, const float* __restrict__ P,
    const float* __restrict__ Wh,
    const float* __restrict__ W1, const float* __restrict__ b1,
    const float* __restrict__ W2, const float* __restrict__ b2,
    float* __restrict__ out)
{
    __shared__ float xs[TT * UU];      // 512 rows x 128 B = 64 KB

    const int L = threadIdx.x;
    const int u = L & 31;
    const int half16 = (L >> 5) << 4;  // 0 for lanes 0-31, 16 for lanes 32-63
    const int b = blockIdx.x;
    const int* trow = tokens + b * TT;

    // wh[kk] = Wh[half16+kk][u] : this lane's 16 rows of its output column
    float wh[16];
    #pragma unroll
    for (int kk = 0; kk < 16; ++kk) wh[kk] = Wh[(half16 + kk) * UU + u];

    // bpermute byte addresses: lower half pulls h_kk (lane kk), upper half
    // pulls h_{16+kk} (lane 16+kk). h is replicated so sources are valid.
    int addrA[16];
    #pragma unroll
    for (int kk = 0; kk < 16; ++kk) addrA[kk] = (half16 + kk) << 2;

    // ---- gather phase: 64 global_load_lds instrs, 8 tokens each ----
    const int sub = L >> 3;            // token-within-group
    const int q   = L & 7;             // 16-B chunk within the 128-B row
    for (int c = 0; c < 8; ++c) {
        int tk8[8];
        #pragma unroll
        for (int i = 0; i < 8; ++i)
            tk8[i] = trow[c * 64 + i * 8 + sub];
        #pragma unroll
        for (int i = 0; i < 8; ++i) {
            const float* src = P + (size_t)tk8[i] * UU + q * 4;
            float* dst = xs + (c * 64 + i * 8) * UU;    // wave-uniform base
            __builtin_amdgcn_global_load_lds(
                (const __attribute__((address_space(1))) void*)src,
                (__attribute__((address_space(3))) void*)dst, 16, 0, 0);
        }
    }
    __syncthreads();   // drains vmcnt: all LDS rows resident

    // ---- scan: pure LDS + VALU, split-k across wave halves ----
    const bool lower = (L < 32);
    float xr[4];
    #pragma unroll
    for (int j = 0; j < 4; ++j) {
        float xv = xs[j * UU + u];
        xr[j] = lower ? xv : 0.f;      // x counted once (lower half only)
    }

    float h = 0.f;

    for (int t = 0; t < TT; t += 4) {
        #pragma unroll
        for (int j = 0; j < 4; ++j) {
            // prefetch next x (wraps at tail into valid memory; discarded)
            float xn = xs[((t + 4 + j) & (TT - 1)) * UU + u];
            xn = lower ? xn : 0.f;

            const int hb = __float_as_int(h);
            float v[16];
            #pragma unroll
            for (int kk = 0; kk < 16; ++kk)
                v[kk] = __int_as_float(__builtin_amdgcn_ds_bpermute(addrA[kk], hb));

            float a0 = fmaf(v[0], wh[0], xr[j]);   // x folded into acc0
            float a1 = v[1] * wh[1];
            float a2 = v[2] * wh[2];
            float a3 = v[3] * wh[3];
            #pragma unroll
            for (int kk = 4; kk < 16; kk += 4) {
                a0 = fmaf(v[kk],     wh[kk],     a0);
                a1 = fmaf(v[kk + 1], wh[kk + 1], a1);
                a2 = fmaf(v[kk + 2], wh[kk + 2], a2);
                a3 = fmaf(v[kk + 3], wh[kk + 3], a3);
            }
            float sh = (a0 + a1) + (a2 + a3);

            // cross-half combine: both halves end with the full sum
            float tot;
#if __has_builtin(__builtin_amdgcn_permlane32_swap)
            {
                auto r = __builtin_amdgcn_permlane32_swap(
                    __float_as_int(sh), __float_as_int(sh), false, false);
                tot = __int_as_float((int)r[0]) + __int_as_float((int)r[1]);
            }
#else
            {
                const int addrX = ((L + 32) & 63) << 2;
                tot = sh + __int_as_float(
                    __builtin_amdgcn_ds_bpermute(addrX, __float_as_int(sh)));
            }
#endif
            h = fast_tanh(tot);
            xr[j] = xn;
        }
    }

    // ---- fused heads (once; readlane-only; h replicated in lanes 0-31) ----
    const int j = threadIdx.x & 15;
    float s = b1[j];
    #pragma unroll
    for (int k = 0; k < UU; ++k) {
        float hk = rdlane(h, k);
        s = fmaf(hk, W1[k * FF1 + j], s);
    }
    float z = b2[0];
    #pragma unroll
    for (int jj = 0; jj < FF1; ++jj) {
        float yj = rdlane(s, jj);
        z = fmaf(yj, W2[jj], z);
    }
    if (threadIdx.x == 0) {
        float e = __builtin_amdgcn_exp2f(-z * 1.4426950408889634f); // e^{-z}
        out[b] = __builtin_amdgcn_rcpf(1.0f + e);
    }
}

// ---------------------------------------------------------------------------
extern "C" void kernel_launch(void* const* d_in, const int* in_sizes, int n_in,
                              void* d_out, int out_size, void* d_ws, size_t ws_size,
                              hipStream_t stream) {
    const int*   tokens = (const int*)  d_in[0];
    const float* emb    = (const float*)d_in[1];
    const float* Wx     = (const float*)d_in[2];
    const float* Wh     = (const float*)d_in[3];
    const float* bias   = (const float*)d_in[4];
    const float* W1     = (const float*)d_in[5];
    const float* b1     = (const float*)d_in[6];
    const float* W2     = (const float*)d_in[7];
    const float* b2     = (const float*)d_in[8];
    float* out = (float*)d_out;

    const int vocab = in_sizes[1] / EE;        // 50000
    float* P = (float*)d_ws;                   // vocab*32*4 = 6.4 MB

    // A: 2048 single-wave blocks, ~25 rows each (8 waves/CU)
    proj_dpp<<<dim3(NWAVE), dim3(64), 0, stream>>>(
        emb, Wx, bias, P, vocab);

    // B: 1 batch row per wave -> 512 blocks x 64 threads (2 blocks/CU)
    scan_heads<<<dim3(BB), dim3(64), 0, stream>>>(
        tokens, P, Wh, W1, b1, W2, b2, out);
}

// Round 2
// 182.687 us; speedup vs baseline: 1.1327x; 1.1327x over previous
//
#include <hip/hip_runtime.h>
#include <hip/hip_bf16.h>
#include <math.h>

// VOCAB=50000, EMBED=256, MAXLEN=512, UNITS=32, F1=16, BATCH=512.
#define TT 512
#define BB 512
#define EE 256
#define UU 32
#define FF1 16
#define NWAVE 2048            // proj waves: 8/CU, 2/SIMD

// 2*log2(e): pre-scale factor so tanh needs no leading multiply.
#define TWO_LOG2E 2.8853900817779268f

__device__ __forceinline__ float rdlane(float v, int lane) {
    return __int_as_float(__builtin_amdgcn_readlane(__float_as_int(v), lane));
}

// v += value from lane (i - N) within the 16-lane DPP row (0 past row edge).
#define DPP_ADD(v, ctrl)                                                    \
    (v) += __int_as_float(__builtin_amdgcn_update_dpp(                      \
        0, __float_as_int(v), (ctrl), 0xf, 0xf, true))

// ---------------------------------------------------------------------------
// Kernel A: P[r][u] = (emb[r] @ Wx[:,u] + bias[u]) * 2*log2(e).
// DPP-reduce GEMV; ~memory-floor bound (~8 us). The 2log2e pre-scale moves
// the tanh input scaling OFF kernel B's serial chain (B's exp2 consumes the
// pre-scaled value directly).
// ---------------------------------------------------------------------------
__global__ __launch_bounds__(64) void proj_dpp(
    const float* __restrict__ emb, const float* __restrict__ Wx,
    const float* __restrict__ bias, float* __restrict__ P, int nrows)
{
    const int L = threadIdx.x;
    const int g = L >> 4;              // u-octet 0..3
    const int c = L & 15;              // k-lane 0..15
    const int wv = blockIdx.x;         // 0..NWAVE-1

    // ---- one-time coalesced w preload: w[kk][uu] = Wx[c+16*kk][g*8+uu]
    float w[16][8];
    #pragma unroll
    for (int kk = 0; kk < 16; ++kk) {
        const float4* src = (const float4*)(Wx + (size_t)(kk * 16 + c) * UU + g * 8);
        float4 a = src[0], b = src[1];
        w[kk][0] = a.x; w[kk][1] = a.y; w[kk][2] = a.z; w[kk][3] = a.w;
        w[kk][4] = b.x; w[kk][5] = b.y; w[kk][6] = b.z; w[kk][7] = b.w;
    }
    float bs[8];
    #pragma unroll
    for (int uu = 0; uu < 8; ++uu) bs[uu] = bias[g * 8 + uu];

    // rows handled by this wave: r = wv + NWAVE*i
    auto rowptr = [&](int i) {
        int r = wv + NWAVE * i;
        if (r >= nrows) r = nrows - 1;             // clamped dummy
        return emb + (size_t)r * EE;
    };

    float xA[16], xB[16];
    {
        const float* rp = rowptr(0);
        #pragma unroll
        for (int kk = 0; kk < 16; ++kk) xA[kk] = rp[kk * 16 + c];
    }

    const int NI = (nrows - 1 - wv) / NWAVE + 1;   // #valid rows (wv < nrows)

    for (int i = 0; i < NI; ++i) {
        // prefetch next row (clamped at tail)
        {
            const float* rp = rowptr(i + 1 < NI ? i + 1 : i);
            #pragma unroll
            for (int kk = 0; kk < 16; ++kk) xB[kk] = rp[kk * 16 + c];
        }

        // partials for this lane's 16 k's x 8 u's
        float p[8];
        #pragma unroll
        for (int uu = 0; uu < 8; ++uu) p[uu] = 0.f;
        #pragma unroll
        for (int kk = 0; kk < 16; ++kk) {
            const float xk = xA[kk];
            #pragma unroll
            for (int uu = 0; uu < 8; ++uu)
                p[uu] = fmaf(xk, w[kk][uu], p[uu]);
        }

        // reduce over the 16 c-lanes (DPP row-of-16); lane c==15 holds sums
        #pragma unroll
        for (int uu = 0; uu < 8; ++uu) {
            DPP_ADD(p[uu], 0x111);   // row_shr:1
            DPP_ADD(p[uu], 0x112);   // row_shr:2
            DPP_ADD(p[uu], 0x114);   // row_shr:4
            DPP_ADD(p[uu], 0x118);   // row_shr:8
        }

        if (c == 15) {
            const int r = wv + NWAVE * i;
            float4 o0, o1;
            o0.x = (p[0] + bs[0]) * TWO_LOG2E;
            o0.y = (p[1] + bs[1]) * TWO_LOG2E;
            o0.z = (p[2] + bs[2]) * TWO_LOG2E;
            o0.w = (p[3] + bs[3]) * TWO_LOG2E;
            o1.x = (p[4] + bs[4]) * TWO_LOG2E;
            o1.y = (p[5] + bs[5]) * TWO_LOG2E;
            o1.z = (p[6] + bs[6]) * TWO_LOG2E;
            o1.w = (p[7] + bs[7]) * TWO_LOG2E;
            float4* dst = (float4*)(P + (size_t)r * UU + g * 8);
            dst[0] = o0; dst[1] = o1;
        }

        #pragma unroll
        for (int kk = 0; kk < 16; ++kk) xA[kk] = xB[kk];
    }
}

// ---------------------------------------------------------------------------
// Kernel B v8: readlane scan (v6 structure) + chain cuts.
// h_t = tanh(x_t + h_{t-1} @ Wh); fused heads + sigmoid.
// One batch row per 64-lane wave (both halves duplicate: broadcast is
// wave-uniform readlane — proven fastest; v7's bpermute put ~120cy of LDS
// latency on the serial chain and regressed).
// Chain cuts vs v6:
//  * P and Wh pre-scaled by 2*log2(e): tanh = 1 - 2*rcp(exp2(a)+1), no mul.
//  * x prefetched 8 steps ahead, all 8 ds_read_b32 issued at block top:
//    ~120cy LDS latency hidden under ~2400cy of compute, scheduler-proof.
//  * all 32 readlanes issued as one group -> single SGPR-hazard boundary.
// ---------------------------------------------------------------------------
__global__ __launch_bounds__(64) void scan_heads(
    const int* __restrict__ tokens, const float* __restrict__ P,
    const float* __restrict__ Wh,
    const float* __restrict__ W1, const float* __restrict__ b1,
    const float* __restrict__ W2, const float* __restrict__ b2,
    float* __restrict__ out)
{
    __shared__ float xs[TT * UU];      // 512 rows x 128 B = 64 KB

    const int L = threadIdx.x;
    const int u = L & 31;
    const int b = blockIdx.x;
    const int* trow = tokens + b * TT;

    // wh[k] = Wh[k][u] * 2log2e : this lane's column of the recurrent matrix
    float wh[UU];
    #pragma unroll
    for (int k = 0; k < UU; ++k) wh[k] = Wh[k * UU + u] * TWO_LOG2E;

    // ---- gather phase: 64 global_load_lds instrs, 8 tokens each ----
    const int sub = L >> 3;            // token-within-group
    const int q   = L & 7;             // 16-B chunk within the 128-B row
    for (int c = 0; c < 8; ++c) {
        int tk8[8];
        #pragma unroll
        for (int i = 0; i < 8; ++i)
            tk8[i] = trow[c * 64 + i * 8 + sub];
        #pragma unroll
        for (int i = 0; i < 8; ++i) {
            const float* src = P + (size_t)tk8[i] * UU + q * 4;
            float* dst = xs + (c * 64 + i * 8) * UU;    // wave-uniform base
            __builtin_amdgcn_global_load_lds(
                (const __attribute__((address_space(1))) void*)src,
                (__attribute__((address_space(3))) void*)dst, 16, 0, 0);
        }
    }
    __syncthreads();   // drains vmcnt: all LDS rows resident

    // ---- scan: pure LDS + VALU ----
    float xr[8];
    #pragma unroll
    for (int j = 0; j < 8; ++j) xr[j] = xs[j * UU + u];

    float h = 0.f;

    for (int t = 0; t < TT; t += 8) {
        // block prefetch: 8 conflict-free ds_read_b32, consumed 8 steps later
        float xn[8];
        #pragma unroll
        for (int j = 0; j < 8; ++j)
            xn[j] = xs[((t + 8 + j) & (TT - 1)) * UU + u];

        #pragma unroll
        for (int j = 0; j < 8; ++j) {
            // broadcast group: 32 readlanes, one hazard boundary
            float hv[UU];
            #pragma unroll
            for (int k = 0; k < UU; ++k) hv[k] = rdlane(h, k);

            float a0 = fmaf(hv[0], wh[0], xr[j]);   // x folded into acc0
            float a1 = hv[1] * wh[1];
            float a2 = hv[2] * wh[2];
            float a3 = hv[3] * wh[3];
            #pragma unroll
            for (int k = 4; k < UU; k += 4) {
                a0 = fmaf(hv[k],     wh[k],     a0);
                a1 = fmaf(hv[k + 1], wh[k + 1], a1);
                a2 = fmaf(hv[k + 2], wh[k + 2], a2);
                a3 = fmaf(hv[k + 3], wh[k + 3], a3);
            }
            // pre-scaled input: tanh(a) = 1 - 2/(exp2(a')+1), a' = 2log2e*a
            float e = __builtin_amdgcn_exp2f((a0 + a1) + (a2 + a3));
            float r = __builtin_amdgcn_rcpf(e + 1.0f);
            h = fmaf(-2.0f, r, 1.0f);
        }

        #pragma unroll
        for (int j = 0; j < 8; ++j) xr[j] = xn[j];
    }

    // ---- fused heads (once; readlane-only; h replicated in all lanes) ----
    const int j = threadIdx.x & 15;
    float s = b1[j];
    #pragma unroll
    for (int k = 0; k < UU; ++k) {
        float hk = rdlane(h, k);
        s = fmaf(hk, W1[k * FF1 + j], s);
    }
    float z = b2[0];
    #pragma unroll
    for (int jj = 0; jj < FF1; ++jj) {
        float yj = rdlane(s, jj);
        z = fmaf(yj, W2[jj], z);
    }
    if (threadIdx.x == 0) {
        float e = __builtin_amdgcn_exp2f(-z * 1.4426950408889634f); // e^{-z}
        out[b] = __builtin_amdgcn_rcpf(1.0f + e);
    }
}

// ---------------------------------------------------------------------------
extern "C" void kernel_launch(void* const* d_in, const int* in_sizes, int n_in,
                              void* d_out, int out_size, void* d_ws, size_t ws_size,
                              hipStream_t stream) {
    const int*   tokens = (const int*)  d_in[0];
    const float* emb    = (const float*)d_in[1];
    const float* Wx     = (const float*)d_in[2];
    const float* Wh     = (const float*)d_in[3];
    const float* bias   = (const float*)d_in[4];
    const float* W1     = (const float*)d_in[5];
    const float* b1     = (const float*)d_in[6];
    const float* W2     = (const float*)d_in[7];
    const float* b2     = (const float*)d_in[8];
    float* out = (float*)d_out;

    const int vocab = in_sizes[1] / EE;        // 50000
    float* P = (float*)d_ws;                   // vocab*32*4 = 6.4 MB

    // A: 2048 single-wave blocks, ~25 rows each (8 waves/CU)
    proj_dpp<<<dim3(NWAVE), dim3(64), 0, stream>>>(
        emb, Wx, bias, P, vocab);

    // B: 1 batch row per wave -> 512 blocks x 64 threads (2 blocks/CU)
    scan_heads<<<dim3(BB), dim3(64), 0, stream>>>(
        tokens, P, Wh, W1, b1, W2, b2, out);
}